// Round 2
// baseline (115.990 us; speedup 1.0000x reference)
//
#include <hip/hip_runtime.h>
#include <hip/hip_fp16.h>

#define S_N 16
#define T_N 400
#define F_N 16
#define SF_N 250
#define G_N 4
#define OUT_ROW 100400   // 400 + 250*400

typedef _Float16 f16x8 __attribute__((ext_vector_type(8)));
typedef float    f32x4 __attribute__((ext_vector_type(4)));

union QU { uint4 u; f16x8 v; };

// LDS: q-table 1600 rows (g*400+t'), each padded to 5 uint4 (80 B, data in
// first 4) -> conflict-spread gathers (row*5 mod 8 covers all bank quads).
// After the table: sA (16x32 f32), sW2 (32x16 f32), sMu (16 f32).
#define LDS_U4     8000                                    // 128,000 B
#define LDS_BYTES  (LDS_U4 * 16 + 512*4 + 512*4 + 16*4)    // 132,160 B

// ---------------------------------------------------------------------------
// Fused kernel. grid 256 = (s, chunk of 6250 samples), block 1024 = 16 waves,
// 1 block/CU (LDS ~129 KiB).
// Phase A: A[j][k] = sum_i Sig[i][j]*W1[i][k] into LDS; stage W2, mu.
// Phase B: each block recomputes q[s] (1600 rows x 32 f16) directly into the
//          padded LDS layout (205K FMA / block ~ 0.5 us -- cheaper than the
//          old qtab HBM round-trip of 1.6 MB write + 25.6 MB read, and kills
//          the second dispatch + serialization gap entirely).
//          25 unshuffled outputs per block keep the old f32 precompute path
//          (identical numerics -> absmax unchanged).
// Main loop: proven LDS-gather + mfma_f32_16x16x32_f16 pipeline, unchanged.
// ---------------------------------------------------------------------------
__global__ __launch_bounds__(1024, 4) void fused_kernel(
    const float* __restrict__ obs,   // (S,T,F)
    const float* __restrict__ mu,    // (F,1)
    const float* __restrict__ Sig,   // (F,F)
    const int*   __restrict__ perm,  // (SF,G,S,T)
    const float* __restrict__ W1,    // (F,32)
    const float* __restrict__ b1,    // (32,)
    const float* __restrict__ W2,    // (32,16)
    const float* __restrict__ b2,    // (16,)
    const float* __restrict__ W3,    // (16,1)
    const float* __restrict__ b3,    // (1,)
    float* __restrict__ out)         // (S, OUT_ROW) f32
{
    extern __shared__ uint4 smem[];
    float* sA  = (float*)(smem + LDS_U4);   // 16 x 32
    float* sW2 = sA + 512;                  // 32 x 16 row-major
    float* sMu = sW2 + 512;                 // 16

    const int tid   = threadIdx.x;          // 0..1023
    const int s     = blockIdx.x >> 4;      // 16 blocks per s
    const int chunk = blockIdx.x & 15;
    const int j0b   = chunk * 6250;         // block's sample range

    // ---- phase A: folded first-layer weights + stage small tensors ----
    if (tid < 512) {
        const int j = tid >> 5, k = tid & 31;
        float acc = 0.f;
        #pragma unroll
        for (int i = 0; i < 16; ++i)
            acc = fmaf(Sig[i * 16 + j], W1[i * 32 + k], acc);
        sA[tid] = acc;
    } else {
        const int e = tid - 512;
        sW2[e] = W2[e];
        if (e < 16) sMu[e] = mu[e];
    }
    __syncthreads();

    // ---- phase B: build q-table rows in LDS (fp16), row = g*400 + t ----
    const float4* obs4 = (const float4*)(obs + (size_t)s * T_N * F_N);
    for (int e = tid; e < 1600; e += 1024) {
        const int g = e / 400;
        const int t = e - g * 400;
        const float4 o = obs4[t * 4 + g];
        const float x0 = o.x - sMu[4 * g + 0];
        const float x1 = o.y - sMu[4 * g + 1];
        const float x2 = o.z - sMu[4 * g + 2];
        const float x3 = o.w - sMu[4 * g + 3];
        const float* Ag = sA + 4 * g * 32;
        __half2 hp[16];
        #pragma unroll
        for (int k2 = 0; k2 < 16; ++k2) {
            float a0 = x0 * Ag[2 * k2];
            a0 = fmaf(x1, Ag[32 + 2 * k2], a0);
            a0 = fmaf(x2, Ag[64 + 2 * k2], a0);
            a0 = fmaf(x3, Ag[96 + 2 * k2], a0);
            float a1 = x0 * Ag[2 * k2 + 1];
            a1 = fmaf(x1, Ag[32 + 2 * k2 + 1], a1);
            a1 = fmaf(x2, Ag[64 + 2 * k2 + 1], a1);
            a1 = fmaf(x3, Ag[96 + 2 * k2 + 1], a1);
            hp[k2] = __floats2half2_rn(a0, a1);
        }
        const uint4* src = (const uint4*)hp;
        uint4* dst = smem + e * 5;
        #pragma unroll
        for (int cc = 0; cc < 4; ++cc) dst[cc] = src[cc];
    }

    // ---- 25 unshuffled outputs for this block, f32 path (old numerics) ----
    if (tid >= 576 && tid < 601) {
        const int t = chunk * 25 + (tid - 576);
        float xm[16];
        {
            const float4 o0 = obs4[t * 4 + 0], o1 = obs4[t * 4 + 1],
                         o2 = obs4[t * 4 + 2], o3 = obs4[t * 4 + 3];
            const float v[16] = {o0.x, o0.y, o0.z, o0.w, o1.x, o1.y, o1.z, o1.w,
                                 o2.x, o2.y, o2.z, o2.w, o3.x, o3.y, o3.z, o3.w};
            #pragma unroll
            for (int j = 0; j < 16; ++j) xm[j] = v[j] - sMu[j];
        }
        float h1[32];
        #pragma unroll
        for (int k = 0; k < 32; ++k) h1[k] = b1[k];
        #pragma unroll
        for (int j = 0; j < 16; ++j) {
            const float xj = xm[j];
            #pragma unroll
            for (int k = 0; k < 32; ++k) h1[k] = fmaf(xj, sA[j * 32 + k], h1[k]);
        }
        #pragma unroll
        for (int k = 0; k < 32; ++k) h1[k] = fmaxf(h1[k], 0.01f * h1[k]);
        float h2[16];
        #pragma unroll
        for (int jj = 0; jj < 16; ++jj) h2[jj] = b2[jj];
        #pragma unroll
        for (int k = 0; k < 32; ++k) {
            const float a = h1[k];
            #pragma unroll
            for (int jj = 0; jj < 16; ++jj) h2[jj] = fmaf(a, sW2[k * 16 + jj], h2[jj]);
        }
        float acc = b3[0];
        #pragma unroll
        for (int jj = 0; jj < 16; ++jj) {
            const float hj = fmaxf(h2[jj], 0.01f * h2[jj]);
            acc = fmaf(hj, W3[jj], acc);
        }
        out[(size_t)s * OUT_ROW + t] = 1.f / (1.f + __expf(-acc));
    }

    // ---- per-lane MFMA fragments (reads phase-A LDS, disjoint from q rows) ----
    const int lane = tid & 63;
    const int wv   = tid >> 6;           // wave 0..15
    const int m    = lane & 15;          // sample-in-group (B col)
    const int c    = lane >> 4;          // k-chunk / quad

    f16x8 afrag, b1v;
    #pragma unroll
    for (int j = 0; j < 8; ++j) {
        // A-frag for A = W2^T: lane l holds A[m=l&15][k=(l>>4)*8+j] = W2[k][m]
        afrag[j] = (_Float16)sW2[(c * 8 + j) * 16 + m];
        b1v[j]   = (_Float16)b1[c * 8 + j];
    }
    const float4 b2v = *(const float4*)(b2 + c * 4);
    const float4 w3v = *(const float4*)(W3 + c * 4);
    const float  b3s = b3[0];
    __syncthreads();

    // ---- main loop: LDS gathers + MFMA (unchanged, proven) ----
    for (int tile = wv; tile < 98; tile += 16) {
        const int jt = j0b + tile * 64;

        // perm indices: lane (m,c) loads all 4 groups of its sample directly
        // (4 lanes share each address -> 1 line per 16 samples)
        int idx[4][4];   // [q][g]
        #pragma unroll
        for (int q = 0; q < 4; ++q) {
            int j = jt + q * 16 + m;
            int jc = j0b + 6249;
            if (j < jc) jc = j;          // clamp (partial last tile)
            const int sf = jc / 400;
            const int t  = jc - sf * 400;
            const int pb = sf * 25600 + s * 400 + t;
            #pragma unroll
            for (int g = 0; g < 4; ++g)
                idx[q][g] = perm[pb + g * 6400];
        }

        float res0, res1, res2, res3;
        #pragma unroll
        for (int q = 0; q < 4; ++q) {
            QU a0, a1, a2, a3;
            a0.u = smem[(idx[q][0]       ) * 5 + c];
            a1.u = smem[( 400 + idx[q][1]) * 5 + c];
            a2.u = smem[( 800 + idx[q][2]) * 5 + c];
            a3.u = smem[(1200 + idx[q][3]) * 5 + c];

            f16x8 h = (a0.v + a1.v) + (a2.v + a3.v) + b1v;
            #pragma unroll
            for (int k = 0; k < 8; ++k) {
                _Float16 x = h[k];
                _Float16 y = x * (_Float16)0.01f;
                h[k] = x > y ? x : y;    // leaky relu -> v_(pk_)max_f16
            }

            f32x4 acc = {0.f, 0.f, 0.f, 0.f};
            acc = __builtin_amdgcn_mfma_f32_16x16x32_f16(afrag, h, acc, 0, 0, 0);

            float p;
            {
                float v0 = acc[0] + b2v.x; v0 = fmaxf(v0, 0.01f * v0); p = v0 * w3v.x;
                float v1 = acc[1] + b2v.y; v1 = fmaxf(v1, 0.01f * v1); p = fmaf(v1, w3v.y, p);
                float v2 = acc[2] + b2v.z; v2 = fmaxf(v2, 0.01f * v2); p = fmaf(v2, w3v.z, p);
                float v3 = acc[3] + b2v.w; v3 = fmaxf(v3, 0.01f * v3); p = fmaf(v3, w3v.w, p);
            }
            p += __shfl_xor(p, 16);
            p += __shfl_xor(p, 32);
            if (q == 0) res0 = p;
            else if (q == 1) res1 = p;
            else if (q == 2) res2 = p;
            else res3 = p;
        }

        // lane l holds sample jt+l's value in res[c(l)] (round q == c)
        float v = res0;
        if (c == 1) v = res1;
        if (c == 2) v = res2;
        if (c == 3) v = res3;
        v += b3s;
        const float sg = 1.f / (1.f + __expf(-v));
        const int j = jt + lane;
        if (j < j0b + 6250)
            out[(size_t)s * OUT_ROW + 400 + j] = sg;
    }
}

extern "C" void kernel_launch(void* const* d_in, const int* in_sizes, int n_in,
                              void* d_out, int out_size, void* d_ws, size_t ws_size,
                              hipStream_t stream) {
    (void)in_sizes; (void)n_in; (void)out_size; (void)d_ws; (void)ws_size;
    const float* obs = (const float*)d_in[0];
    const float* mu  = (const float*)d_in[1];
    const float* Sig = (const float*)d_in[2];
    const int*   prm = (const int*)d_in[3];
    const float* W1  = (const float*)d_in[4];
    const float* b1  = (const float*)d_in[5];
    const float* W2  = (const float*)d_in[6];
    const float* b2  = (const float*)d_in[7];
    const float* W3  = (const float*)d_in[8];
    const float* b3  = (const float*)d_in[9];
    float* out = (float*)d_out;

    // allow >64 KiB dynamic LDS (no-op if already permitted)
    (void)hipFuncSetAttribute((const void*)fused_kernel,
                              hipFuncAttributeMaxDynamicSharedMemorySize,
                              LDS_BYTES);

    hipLaunchKernelGGL(fused_kernel, dim3(256), dim3(1024), LDS_BYTES, stream,
                       obs, mu, Sig, prm, W1, b1, W2, b2, W3, b3, out);
}

// Round 3
// 114.728 us; speedup vs baseline: 1.0110x; 1.0110x over previous
//
#include <hip/hip_runtime.h>
#include <hip/hip_fp16.h>

#define S_N 16
#define T_N 400
#define F_N 16
#define SF_N 250
#define G_N 4
#define OUT_ROW 100400   // 400 + 250*400

typedef _Float16 f16x8 __attribute__((ext_vector_type(8)));
typedef float    f32x4 __attribute__((ext_vector_type(4)));

union QU { uint4 u; f16x8 v; };

// LDS: q-table 1600 rows (g*400+t'), each padded to 5 uint4 (80 B, data in
// first 4) -> conflict-spread gathers. After the table: sA (16x32 f32),
// sW2 (32x16 f32), sMu (16 f32), then per-wave perm-index scratch
// (16 waves x 256 ints = 16 KB).
#define LDS_U4     8000                                    // 128,000 B
#define SIDX_INTS  4096                                    // 16 waves * 256
#define LDS_BYTES  (LDS_U4 * 16 + 512*4 + 512*4 + 16*4 + SIDX_INTS*4) // 148,544

// ---------------------------------------------------------------------------
// Fused kernel. grid 256 = (s, chunk of 6250 samples), block 1024 = 16 waves,
// 1 block/CU.
// Round-2 profile: 54 us, HBM 5%, VALU 30%, Mfma 1% -> off-counter limiter =
// TA/TCP request rate: 16 global_load_dword per tile (64 lanes, 16 unique
// addrs) = 25.7M lane-requests ~= 42 us at 1/cyc/CU. This round: coalesced
// perm loads (2 x dwordx2 per lane per tile = 1 KB/wave-instr-pair) staged
// through a per-wave LDS scratch; index redistribution via broadcast
// ds_read_b32. 8x fewer TA lane-requests; global load for tile n+1 issued
// before tile n's compute (latency hidden). Index values bit-identical.
// ---------------------------------------------------------------------------
__global__ __launch_bounds__(1024, 4) void fused_kernel(
    const float* __restrict__ obs,   // (S,T,F)
    const float* __restrict__ mu,    // (F,1)
    const float* __restrict__ Sig,   // (F,F)
    const int*   __restrict__ perm,  // (SF,G,S,T)
    const float* __restrict__ W1,    // (F,32)
    const float* __restrict__ b1,    // (32,)
    const float* __restrict__ W2,    // (32,16)
    const float* __restrict__ b2,    // (16,)
    const float* __restrict__ W3,    // (16,1)
    const float* __restrict__ b3,    // (1,)
    float* __restrict__ out)         // (S, OUT_ROW) f32
{
    extern __shared__ uint4 smem[];
    float* sA   = (float*)(smem + LDS_U4);  // 16 x 32
    float* sW2  = sA + 512;                 // 32 x 16 row-major
    float* sMu  = sW2 + 512;                // 16
    int*   sIdx = (int*)(sMu + 16);         // 16 waves x 256 ints (16B-aligned)

    const int tid   = threadIdx.x;          // 0..1023
    const int s     = blockIdx.x >> 4;      // 16 blocks per s
    const int chunk = blockIdx.x & 15;
    const int j0b   = chunk * 6250;         // block's sample range

    // ---- phase A: folded first-layer weights + stage small tensors ----
    if (tid < 512) {
        const int j = tid >> 5, k = tid & 31;
        float acc = 0.f;
        #pragma unroll
        for (int i = 0; i < 16; ++i)
            acc = fmaf(Sig[i * 16 + j], W1[i * 32 + k], acc);
        sA[tid] = acc;
    } else {
        const int e = tid - 512;
        sW2[e] = W2[e];
        if (e < 16) sMu[e] = mu[e];
    }
    __syncthreads();

    // ---- phase B: build q-table rows in LDS (fp16), row = g*400 + t ----
    const float4* obs4 = (const float4*)(obs + (size_t)s * T_N * F_N);
    for (int e = tid; e < 1600; e += 1024) {
        const int g = e / 400;
        const int t = e - g * 400;
        const float4 o = obs4[t * 4 + g];
        const float x0 = o.x - sMu[4 * g + 0];
        const float x1 = o.y - sMu[4 * g + 1];
        const float x2 = o.z - sMu[4 * g + 2];
        const float x3 = o.w - sMu[4 * g + 3];
        const float* Ag = sA + 4 * g * 32;
        __half2 hp[16];
        #pragma unroll
        for (int k2 = 0; k2 < 16; ++k2) {
            float a0 = x0 * Ag[2 * k2];
            a0 = fmaf(x1, Ag[32 + 2 * k2], a0);
            a0 = fmaf(x2, Ag[64 + 2 * k2], a0);
            a0 = fmaf(x3, Ag[96 + 2 * k2], a0);
            float a1 = x0 * Ag[2 * k2 + 1];
            a1 = fmaf(x1, Ag[32 + 2 * k2 + 1], a1);
            a1 = fmaf(x2, Ag[64 + 2 * k2 + 1], a1);
            a1 = fmaf(x3, Ag[96 + 2 * k2 + 1], a1);
            hp[k2] = __floats2half2_rn(a0, a1);
        }
        const uint4* src = (const uint4*)hp;
        uint4* dst = smem + e * 5;
        #pragma unroll
        for (int cc = 0; cc < 4; ++cc) dst[cc] = src[cc];
    }

    // ---- 25 unshuffled outputs for this block, f32 path (old numerics) ----
    if (tid >= 576 && tid < 601) {
        const int t = chunk * 25 + (tid - 576);
        float xm[16];
        {
            const float4 o0 = obs4[t * 4 + 0], o1 = obs4[t * 4 + 1],
                         o2 = obs4[t * 4 + 2], o3 = obs4[t * 4 + 3];
            const float v[16] = {o0.x, o0.y, o0.z, o0.w, o1.x, o1.y, o1.z, o1.w,
                                 o2.x, o2.y, o2.z, o2.w, o3.x, o3.y, o3.z, o3.w};
            #pragma unroll
            for (int j = 0; j < 16; ++j) xm[j] = v[j] - sMu[j];
        }
        float h1[32];
        #pragma unroll
        for (int k = 0; k < 32; ++k) h1[k] = b1[k];
        #pragma unroll
        for (int j = 0; j < 16; ++j) {
            const float xj = xm[j];
            #pragma unroll
            for (int k = 0; k < 32; ++k) h1[k] = fmaf(xj, sA[j * 32 + k], h1[k]);
        }
        #pragma unroll
        for (int k = 0; k < 32; ++k) h1[k] = fmaxf(h1[k], 0.01f * h1[k]);
        float h2[16];
        #pragma unroll
        for (int jj = 0; jj < 16; ++jj) h2[jj] = b2[jj];
        #pragma unroll
        for (int k = 0; k < 32; ++k) {
            const float a = h1[k];
            #pragma unroll
            for (int jj = 0; jj < 16; ++jj) h2[jj] = fmaf(a, sW2[k * 16 + jj], h2[jj]);
        }
        float acc = b3[0];
        #pragma unroll
        for (int jj = 0; jj < 16; ++jj) {
            const float hj = fmaxf(h2[jj], 0.01f * h2[jj]);
            acc = fmaf(hj, W3[jj], acc);
        }
        out[(size_t)s * OUT_ROW + t] = 1.f / (1.f + __expf(-acc));
    }

    // ---- per-lane MFMA fragments (reads phase-A LDS, disjoint from q rows) ----
    const int lane = tid & 63;
    const int wv   = tid >> 6;           // wave 0..15
    const int m    = lane & 15;          // sample-in-group (B col)
    const int c    = lane >> 4;          // k-chunk / quad

    f16x8 afrag, b1v;
    #pragma unroll
    for (int j = 0; j < 8; ++j) {
        // A-frag for A = W2^T: lane l holds A[m=l&15][k=(l>>4)*8+j] = W2[k][m]
        afrag[j] = (_Float16)sW2[(c * 8 + j) * 16 + m];
        b1v[j]   = (_Float16)b1[c * 8 + j];
    }
    const float4 b2v = *(const float4*)(b2 + c * 4);
    const float4 w3v = *(const float4*)(W3 + c * 4);
    const float  b3s = b3[0];
    __syncthreads();

    // ---- coalesced perm producer: lane (gP,mP) loads samples jt+4*mP..+3 of
    //      group gP (2 x int2, always 8B-aligned since jA is even). Rare
    //      boundary/clamp packs take the scalar path (identical semantics). --
    const int gP   = lane >> 4;
    const int mP   = lane & 15;
    const int jmax = j0b + 6249;
    int* const sIdxW = sIdx + (wv << 8);     // this wave's 256-int scratch

    auto loadPerm = [&](int jt_) -> int4 {
        const int jA = jt_ + 4 * mP;
        int4 r;
        const int sfA = jA / 400;
        const int t0  = jA - sfA * 400;
        if (jA + 3 <= jmax && t0 <= 396) {
            const int* p = perm + sfA * 25600 + gP * 6400 + s * 400 + t0;
            const int2 lo = *(const int2*)(p);
            const int2 hi = *(const int2*)(p + 2);
            r.x = lo.x; r.y = lo.y; r.z = hi.x; r.w = hi.y;
        } else {
            #pragma unroll
            for (int i = 0; i < 4; ++i) {
                int j = jA + i; if (j > jmax) j = jmax;
                const int sf = j / 400;
                const int t  = j - sf * 400;
                ((int*)&r)[i] = perm[sf * 25600 + gP * 6400 + s * 400 + t];
            }
        }
        return r;
    };

    int4 vperm = loadPerm(j0b + wv * 64);    // prologue: tile 'wv'

    // ---- main loop: LDS gathers + MFMA ----
    for (int tile = wv; tile < 98; tile += 16) {
        const int jt = j0b + tile * 64;

        // stage this tile's 256 perm indices: [g][64] ints, contiguous write
        *(int4*)(sIdxW + gP * 64 + 4 * mP) = vperm;

        // redistribute: lane (m,c) reads its 16 indices (broadcast ds_read_b32)
        int idx[4][4];   // [q][g]
        #pragma unroll
        for (int q = 0; q < 4; ++q)
            #pragma unroll
            for (int g = 0; g < 4; ++g)
                idx[q][g] = sIdxW[g * 64 + q * 16 + m];

        // prefetch next tile's perm (clamped-safe past the end)
        vperm = loadPerm(jt + 1024);

        float res0, res1, res2, res3;
        #pragma unroll
        for (int q = 0; q < 4; ++q) {
            QU a0, a1, a2, a3;
            a0.u = smem[(idx[q][0]       ) * 5 + c];
            a1.u = smem[( 400 + idx[q][1]) * 5 + c];
            a2.u = smem[( 800 + idx[q][2]) * 5 + c];
            a3.u = smem[(1200 + idx[q][3]) * 5 + c];

            f16x8 h = (a0.v + a1.v) + (a2.v + a3.v) + b1v;
            #pragma unroll
            for (int k = 0; k < 8; ++k) {
                _Float16 x = h[k];
                _Float16 y = x * (_Float16)0.01f;
                h[k] = x > y ? x : y;    // leaky relu -> v_(pk_)max_f16
            }

            f32x4 acc = {0.f, 0.f, 0.f, 0.f};
            acc = __builtin_amdgcn_mfma_f32_16x16x32_f16(afrag, h, acc, 0, 0, 0);

            float p;
            {
                float v0 = acc[0] + b2v.x; v0 = fmaxf(v0, 0.01f * v0); p = v0 * w3v.x;
                float v1 = acc[1] + b2v.y; v1 = fmaxf(v1, 0.01f * v1); p = fmaf(v1, w3v.y, p);
                float v2 = acc[2] + b2v.z; v2 = fmaxf(v2, 0.01f * v2); p = fmaf(v2, w3v.z, p);
                float v3 = acc[3] + b2v.w; v3 = fmaxf(v3, 0.01f * v3); p = fmaf(v3, w3v.w, p);
            }
            p += __shfl_xor(p, 16);
            p += __shfl_xor(p, 32);
            if (q == 0) res0 = p;
            else if (q == 1) res1 = p;
            else if (q == 2) res2 = p;
            else res3 = p;
        }

        // lane l holds sample jt+l's value in res[c(l)] (round q == c)
        float v = res0;
        if (c == 1) v = res1;
        if (c == 2) v = res2;
        if (c == 3) v = res3;
        v += b3s;
        const float sg = 1.f / (1.f + __expf(-v));
        const int j = jt + lane;
        if (j < j0b + 6250)
            out[(size_t)s * OUT_ROW + 400 + j] = sg;
    }
}

extern "C" void kernel_launch(void* const* d_in, const int* in_sizes, int n_in,
                              void* d_out, int out_size, void* d_ws, size_t ws_size,
                              hipStream_t stream) {
    (void)in_sizes; (void)n_in; (void)out_size; (void)d_ws; (void)ws_size;
    const float* obs = (const float*)d_in[0];
    const float* mu  = (const float*)d_in[1];
    const float* Sig = (const float*)d_in[2];
    const int*   prm = (const int*)d_in[3];
    const float* W1  = (const float*)d_in[4];
    const float* b1  = (const float*)d_in[5];
    const float* W2  = (const float*)d_in[6];
    const float* b2  = (const float*)d_in[7];
    const float* W3  = (const float*)d_in[8];
    const float* b3  = (const float*)d_in[9];
    float* out = (float*)d_out;

    // allow >64 KiB dynamic LDS (no-op if already permitted)
    (void)hipFuncSetAttribute((const void*)fused_kernel,
                              hipFuncAttributeMaxDynamicSharedMemorySize,
                              LDS_BYTES);

    hipLaunchKernelGGL(fused_kernel, dim3(256), dim3(1024), LDS_BYTES, stream,
                       obs, mu, Sig, prm, W1, b1, W2, b2, W3, b3, out);
}